// Round 1
// baseline (1157.451 us; speedup 1.0000x reference)
//
#include <hip/hip_runtime.h>

// Problem constants (fixed by setup_inputs)
#define S_LEN   2048
#define D_DIM   128
#define KH_N    4
#define QH_N    4
#define H_N     (KH_N * QH_N)
#define SINK_N  16
#define MAXW    160    // >= window(128) + sink(16)
#define MAXC    1920   // >= S - SINK - window = 1904

// ---------------------------------------------------------------------------
// Kernel 1: pack sign bits (q >= 0) into 2 x u64 per (row of 128 floats).
// Rows 0 .. H*S-1 are query rows; rows H*S .. H*S+KH*S-1 are key rows.
// One wave per row; __ballot builds the 64-bit masks directly.
// ---------------------------------------------------------------------------
__global__ __launch_bounds__(256) void pack_signs_kernel(
    const float* __restrict__ q, const float* __restrict__ k,
    unsigned long long* __restrict__ signs) {
  int gid  = blockIdx.x * 256 + threadIdx.x;
  int wave = gid >> 6;
  int lane = gid & 63;
  const int QROWS = H_N * S_LEN;
  const float* src = (wave < QROWS) ? (q + (size_t)wave * D_DIM)
                                    : (k + (size_t)(wave - QROWS) * D_DIM);
  unsigned long long b0 = __ballot(src[lane] >= 0.0f);
  unsigned long long b1 = __ballot(src[lane + 64] >= 0.0f);
  if (lane == 0) {
    signs[(size_t)wave * 2 + 0] = b0;
    signs[(size_t)wave * 2 + 1] = b1;
  }
}

// ---------------------------------------------------------------------------
// Kernel 2: one block (256 thr = 4 waves) per (kh, s) query row.
//   Stage 1: LSH scan of long-term region -> candidate list in LDS
//   Stage 2: score window + candidates for all 4 qh (k row read once)
//   Stage 3: per-wave (qh) exact top-64 threshold via radix-64 select
//   Stage 4: per-wave softmax + p*V accumulate, lane owns dims {2*lane, 2*lane+1}
// ---------------------------------------------------------------------------
__global__ __launch_bounds__(256) void attn_kernel(
    const float* __restrict__ query, const float* __restrict__ key,
    const float* __restrict__ value, const float* __restrict__ thr,
    const int* __restrict__ p_topk, const int* __restrict__ p_wsz,
    const unsigned long long* __restrict__ signs,
    float* __restrict__ out) {
  const int row  = blockIdx.x;         // 0 .. KH*S-1
  const int kh   = row >> 11;          // / 2048
  const int s    = row & (S_LEN - 1);
  const int tid  = threadIdx.x;
  const int lane = tid & 63;
  const int qh   = tid >> 6;           // wave id == query head within group

  __shared__ __align__(16) float q_sh[QH_N][D_DIM];
  __shared__ unsigned long long qs_sh[QH_N][2];
  __shared__ unsigned short widx[MAXW];
  __shared__ unsigned short cidx[MAXC];
  __shared__ float wsc[QH_N][MAXW];
  __shared__ float csc[QH_N][MAXC];
  __shared__ unsigned int hist[QH_N][64];
  __shared__ int ncand_sh;

  const int   topk   = *p_topk;   // 64
  const int   wsz    = *p_wsz;    // 128
  const float thresh = thr[kh];   // 70.0

  // load q rows for the 4 heads of this group + their sign words
  for (int i = tid; i < QH_N * D_DIM; i += 256) {
    int h = i >> 7, d = i & (D_DIM - 1);
    q_sh[h][d] = query[((size_t)(kh * QH_N + h) * S_LEN + s) * D_DIM + d];
  }
  if (tid < QH_N * 2) {
    int h = tid >> 1, w = tid & 1;
    qs_sh[h][w] = signs[((size_t)(kh * QH_N + h) * S_LEN + s) * 2 + w];
  }
  if (tid == 0) ncand_sh = 0;

  // window index list: sinks [0,nsink) plus [wlo, s]
  int wlo = s - (wsz - 1); if (wlo < 0) wlo = 0;
  int nsink = wlo < SINK_N ? wlo : SINK_N;
  int nw = nsink + (s - wlo + 1);
  if (nw > MAXW) nw = MAXW;  // safety (never hit with wsz=128)
  for (int e = tid; e < nw; e += 256)
    widx[e] = (unsigned short)(e < nsink ? e : wlo + (e - nsink));
  __syncthreads();

  // ---- Stage 1: LSH candidate scan over long-term region [SINK, s-wsz] ----
  unsigned long long qs0[QH_N], qs1[QH_N];
#pragma unroll
  for (int h = 0; h < QH_N; h++) { qs0[h] = qs_sh[h][0]; qs1[h] = qs_sh[h][1]; }
  const unsigned long long* ksg =
      signs + ((size_t)H_N * S_LEN + (size_t)kh * S_LEN) * 2;
  int lt_hi = s - wsz;  // inclusive
  for (int l = SINK_N + tid; l <= lt_hi; l += 256) {
    ulonglong2 kk = *(const ulonglong2*)(ksg + 2 * l);
    int best = 0;
#pragma unroll
    for (int h = 0; h < QH_N; h++) {
      int m = 128 - __popcll(qs0[h] ^ kk.x) - __popcll(qs1[h] ^ kk.y);
      best = best > m ? best : m;
    }
    if ((float)best > thresh) {  // match count > threshold (>= 71)
      int pos = atomicAdd(&ncand_sh, 1);
      if (pos < MAXC) cidx[pos] = (unsigned short)l;
    }
  }
  __syncthreads();
  int nc = ncand_sh < MAXC ? ncand_sh : MAXC;
  int ntot = nw + nc;

  // ---- Stage 2: raw scores for window + candidates, all 4 qh per k read ----
  const float scale = 0.088388347648318447f;  // 1/sqrt(128)
  const float* kbase = key + (size_t)kh * S_LEN * D_DIM;
  for (int e = tid; e < ntot; e += 256) {
    int l = (e < nw) ? (int)widx[e] : (int)cidx[e - nw];
    const float* kp = kbase + (size_t)l * D_DIM;
    float a0 = 0.f, a1 = 0.f, a2 = 0.f, a3 = 0.f;
#pragma unroll 8
    for (int d = 0; d < D_DIM; d += 4) {
      float4 kv = *(const float4*)(kp + d);
      float4 q0 = *(const float4*)&q_sh[0][d];
      float4 q1 = *(const float4*)&q_sh[1][d];
      float4 q2 = *(const float4*)&q_sh[2][d];
      float4 q3 = *(const float4*)&q_sh[3][d];
      a0 += kv.x*q0.x + kv.y*q0.y + kv.z*q0.z + kv.w*q0.w;
      a1 += kv.x*q1.x + kv.y*q1.y + kv.z*q1.z + kv.w*q1.w;
      a2 += kv.x*q2.x + kv.y*q2.y + kv.z*q2.z + kv.w*q2.w;
      a3 += kv.x*q3.x + kv.y*q3.y + kv.z*q3.z + kv.w*q3.w;
    }
    if (e < nw) {
      wsc[0][e] = a0*scale; wsc[1][e] = a1*scale;
      wsc[2][e] = a2*scale; wsc[3][e] = a3*scale;
    } else {
      int c = e - nw;
      csc[0][c] = a0*scale; csc[1][c] = a1*scale;
      csc[2][c] = a2*scale; csc[3][c] = a3*scale;
    }
  }
  __syncthreads();

  // ---- Stage 3: per-wave exact top-k threshold (radix-64, 6 passes) ----
  // ordered-uint key: monotone increasing with float value
  bool selAll = (nc <= topk);
  unsigned int tkey = 0;
  bool useTie = false;
  int l_cut = S_LEN;
  if (!selAll) {  // uniform across all 4 waves -> barriers inside are safe
    unsigned int prefix = 0;
    int want = topk;
    for (int pass = 0; pass < 6; pass++) {
      int sh = 30 - pass * 6;  // 30,24,18,12,6,0
      hist[qh][lane] = 0;
      __syncthreads();
      for (int c = lane; c < nc; c += 64) {
        unsigned int b = __float_as_uint(csc[qh][c]);
        unsigned int u = (b & 0x80000000u) ? ~b : (b | 0x80000000u);
        bool match = (pass == 0) || ((u >> (sh + 6)) == prefix);
        if (match) atomicAdd(&hist[qh][(u >> sh) & 63u], 1u);
      }
      __syncthreads();
      unsigned int cnt = hist[qh][lane];
      unsigned int suf = cnt;  // suffix sum over lanes (digit bins)
#pragma unroll
      for (int off = 1; off < 64; off <<= 1) {
        unsigned int t = __shfl_down(suf, off);
        if (lane + off < 64) suf += t;
      }
      unsigned long long mk = __ballot(suf >= (unsigned int)want);
      int dg = 63 - __clzll(mk);  // digit of the want-th largest
      unsigned int suf_dg = __shfl(suf, dg);
      unsigned int cnt_dg = __shfl(cnt, dg);
      want -= (int)(suf_dg - cnt_dg);   // rank within chosen digit
      prefix = (prefix << 6) | (unsigned int)dg;
    }
    tkey = prefix;  // exact ordered key of the 64th-largest score
    // tie accounting (ties are measure-zero but handle exactly, lowest l wins)
    int cgt = 0, ceq = 0;
    for (int c = lane; c < nc; c += 64) {
      unsigned int b = __float_as_uint(csc[qh][c]);
      unsigned int u = (b & 0x80000000u) ? ~b : (b | 0x80000000u);
      cgt += (u > tkey);
      ceq += (u == tkey);
    }
#pragma unroll
    for (int off = 32; off > 0; off >>= 1) {
      cgt += __shfl_down(cgt, off);
      ceq += __shfl_down(ceq, off);
    }
    cgt = __shfl(cgt, 0); ceq = __shfl(ceq, 0);
    int rem = topk - cgt;
    if (ceq > rem) {  // rare: pick rem smallest-l among equals
      useTie = true;
      int lo = 0, hi = S_LEN - 1;
      while (lo < hi) {
        int mid = (lo + hi) >> 1;
        int cn = 0;
        for (int c = lane; c < nc; c += 64) {
          unsigned int b = __float_as_uint(csc[qh][c]);
          unsigned int u = (b & 0x80000000u) ? ~b : (b | 0x80000000u);
          cn += (u == tkey && (int)cidx[c] <= mid);
        }
#pragma unroll
        for (int off = 32; off > 0; off >>= 1) cn += __shfl_down(cn, off);
        cn = __shfl(cn, 0);
        if (cn >= rem) hi = mid; else lo = mid + 1;
      }
      l_cut = lo;
    }
  }

  // ---- Stage 4: per-wave softmax over window + selected candidates ----
  float mx = -1e30f;
  for (int e = lane; e < ntot; e += 64) {
    float sc; bool inc;
    if (e < nw) { sc = wsc[qh][e]; inc = true; }
    else {
      int c = e - nw; sc = csc[qh][c];
      if (selAll) inc = true;
      else {
        unsigned int b = __float_as_uint(sc);
        unsigned int u = (b & 0x80000000u) ? ~b : (b | 0x80000000u);
        inc = (u > tkey) || (u == tkey && (!useTie || (int)cidx[c] <= l_cut));
      }
    }
    if (inc && sc > mx) mx = sc;
  }
#pragma unroll
  for (int off = 32; off > 0; off >>= 1) mx = fmaxf(mx, __shfl_down(mx, off));
  mx = __shfl(mx, 0);

  float sum = 0.0f;
  for (int e = lane; e < ntot; e += 64) {
    float p;
    if (e < nw) { p = __expf(wsc[qh][e] - mx); wsc[qh][e] = p; }
    else {
      int c = e - nw; float sc = csc[qh][c];
      bool inc;
      if (selAll) inc = true;
      else {
        unsigned int b = __float_as_uint(sc);
        unsigned int u = (b & 0x80000000u) ? ~b : (b | 0x80000000u);
        inc = (u > tkey) || (u == tkey && (!useTie || (int)cidx[c] <= l_cut));
      }
      p = inc ? __expf(sc - mx) : 0.0f;
      csc[qh][c] = p;
    }
    sum += p;
  }
#pragma unroll
  for (int off = 32; off > 0; off >>= 1) sum += __shfl_down(sum, off);
  sum = __shfl(sum, 0);
  float rinv = 1.0f / sum;

  __syncthreads();  // make p values visible across lanes (uniform barrier)

  // p * V accumulate: lane owns dims d0, d0+1 -> coalesced float2 loads
  float accx = 0.f, accy = 0.f;
  const int d0 = lane * 2;
  const float* vbase = value + (size_t)kh * S_LEN * D_DIM + d0;
  for (int e = 0; e < ntot; e++) {
    float p = (e < nw) ? wsc[qh][e] : csc[qh][e - nw];  // LDS broadcast
    if (p == 0.0f) continue;                            // wave-uniform skip
    int l = (e < nw) ? (int)widx[e] : (int)cidx[e - nw];
    float2 v2 = *(const float2*)(vbase + (size_t)l * D_DIM);
    accx += p * v2.x;
    accy += p * v2.y;
  }
  size_t o = (size_t)s * (H_N * D_DIM) + (size_t)(kh * QH_N + qh) * D_DIM + d0;
  out[o]     = accx * rinv;
  out[o + 1] = accy * rinv;
}

// ---------------------------------------------------------------------------
extern "C" void kernel_launch(void* const* d_in, const int* in_sizes, int n_in,
                              void* d_out, int out_size, void* d_ws, size_t ws_size,
                              hipStream_t stream) {
  const float* query = (const float*)d_in[0];
  const float* key   = (const float*)d_in[1];
  const float* value = (const float*)d_in[2];
  const float* thr   = (const float*)d_in[3];
  const int* p_topk  = (const int*)d_in[4];
  const int* p_wsz   = (const int*)d_in[5];
  float* out = (float*)d_out;
  unsigned long long* signs = (unsigned long long*)d_ws;  // (H+KH)*S*2 u64 = 640 KB

  // Kernel 1: sign packing — (H+KH)*S waves, 4 waves per 256-thread block
  int total_waves = (H_N + KH_N) * S_LEN;   // 40960
  int pack_blocks = total_waves / 4;        // 10240
  pack_signs_kernel<<<pack_blocks, 256, 0, stream>>>(query, key, signs);

  // Kernel 2: one block per (kh, s)
  attn_kernel<<<KH_N * S_LEN, 256, 0, stream>>>(
      query, key, value, thr, p_topk, p_wsz, signs, out);
}

// Round 2
// 571.826 us; speedup vs baseline: 2.0241x; 2.0241x over previous
//
#include <hip/hip_runtime.h>

// Problem constants (fixed by setup_inputs)
#define S_LEN   2048
#define D_DIM   128
#define KH_N    4
#define QH_N    4
#define H_N     (KH_N * QH_N)
#define SINK_N  16
#define MAXW    160    // >= window(128) + sink(16)
#define MAXC    1920   // >= S - SINK - window = 1904
#define NREG    30     // ceil(MAXC/64) candidate scores per lane
#define CHUNK   512    // candidates scored per LDS chunk
#define MAXSEL  224    // >= window(144) + top_k(64) + pad

__device__ __forceinline__ void lds_fence() {
  asm volatile("s_waitcnt lgkmcnt(0)" ::: "memory");
}

__device__ __forceinline__ unsigned int okey(float f) {
  unsigned int b = __float_as_uint(f);
  return (b & 0x80000000u) ? ~b : (b | 0x80000000u);
}

// ---------------------------------------------------------------------------
// Kernel 1: pack sign bits (x >= 0) into 2 x u64 per row of 128 floats.
// Rows 0 .. H*S-1 = query rows; rows H*S .. H*S+KH*S-1 = key rows.
// ---------------------------------------------------------------------------
__global__ __launch_bounds__(256) void pack_signs_kernel(
    const float* __restrict__ q, const float* __restrict__ k,
    unsigned long long* __restrict__ signs) {
  int gid  = blockIdx.x * 256 + threadIdx.x;
  int wave = gid >> 6;
  int lane = gid & 63;
  const int QROWS = H_N * S_LEN;
  const float* src = (wave < QROWS) ? (q + (size_t)wave * D_DIM)
                                    : (k + (size_t)(wave - QROWS) * D_DIM);
  unsigned long long b0 = __ballot(src[lane] >= 0.0f);
  unsigned long long b1 = __ballot(src[lane + 64] >= 0.0f);
  if (lane == 0) {
    signs[(size_t)wave * 2 + 0] = b0;
    signs[(size_t)wave * 2 + 1] = b1;
  }
}

// ---------------------------------------------------------------------------
// Kernel 2: one block (4 waves) per (kh, s); wave == qh within the GQA group.
// ---------------------------------------------------------------------------
__global__ __launch_bounds__(256, 4) void attn_kernel(
    const float* __restrict__ query, const float* __restrict__ key,
    const float* __restrict__ value, const float* __restrict__ thr,
    const int* __restrict__ p_topk, const int* __restrict__ p_wsz,
    const unsigned long long* __restrict__ signs,
    float* __restrict__ out) {
  const int row  = blockIdx.x;                    // 0 .. KH*S-1
  const int kh   = row >> 11;
  const int s    = (S_LEN - 1) - (row & (S_LEN - 1));  // big-s blocks first
  const int tid  = threadIdx.x;
  const int lane = tid & 63;
  const int qh   = tid >> 6;

  __shared__ __align__(16) float q_sh[QH_N][D_DIM];          // 2 KB
  __shared__ unsigned long long qs_sh[QH_N][2];
  __shared__ unsigned short widx[MAXW];                      // 320 B
  __shared__ unsigned short cidx[MAXC];                      // 3.8 KB
  __shared__ float wsc[QH_N][MAXW];                          // 2.5 KB
  __shared__ __align__(16) float cbuf[QH_N][CHUNK];          // 8 KB
  __shared__ unsigned int hist[QH_N][64];                    // 1 KB
  __shared__ unsigned short sel_idx[QH_N][MAXSEL];           // 1.75 KB
  __shared__ float sel_p[QH_N][MAXSEL];                      // 3.5 KB
  __shared__ int ncand_sh;
  __shared__ int nsel_sh[QH_N];

  const int   topk   = *p_topk;   // 64
  const int   wsz    = *p_wsz;    // 128
  const float thresh = thr[kh];   // 70.0

  // ---- load q rows + sign words for the 4 heads of this group ----
  for (int i = tid; i < QH_N * D_DIM; i += 256) {
    int h = i >> 7, d = i & (D_DIM - 1);
    q_sh[h][d] = query[((size_t)(kh * QH_N + h) * S_LEN + s) * D_DIM + d];
  }
  if (tid < QH_N * 2) {
    int h = tid >> 1, w = tid & 1;
    qs_sh[h][w] = signs[((size_t)(kh * QH_N + h) * S_LEN + s) * 2 + w];
  }
  if (tid == 0) ncand_sh = 0;

  int wlo = s - (wsz - 1); if (wlo < 0) wlo = 0;
  int nsink = wlo < SINK_N ? wlo : SINK_N;
  int nw = nsink + (s - wlo + 1);
  if (nw > MAXW) nw = MAXW;
  for (int e = tid; e < nw; e += 256)
    widx[e] = (unsigned short)(e < nsink ? e : wlo + (e - nsink));
  __syncthreads();

  // ---- Stage 1: LSH scan over [SINK, s-wsz], ballot-compacted append ----
  unsigned long long qs0[QH_N], qs1[QH_N];
#pragma unroll
  for (int h = 0; h < QH_N; h++) { qs0[h] = qs_sh[h][0]; qs1[h] = qs_sh[h][1]; }
  const unsigned long long* ksg =
      signs + ((size_t)H_N * S_LEN + (size_t)kh * S_LEN) * 2;
  int lt_hi = s - wsz;  // inclusive
  for (int l0 = SINK_N; l0 <= lt_hi; l0 += 256) {
    int l = l0 + tid;
    bool match = false;
    if (l <= lt_hi) {
      ulonglong2 kk = *(const ulonglong2*)(ksg + 2 * l);
      int best = 0;
#pragma unroll
      for (int h = 0; h < QH_N; h++) {
        int m = 128 - __popcll(qs0[h] ^ kk.x) - __popcll(qs1[h] ^ kk.y);
        best = best > m ? best : m;
      }
      match = ((float)best > thresh);
    }
    unsigned long long m = __ballot(match);
    if (m) {
      int base = 0;
      if (lane == 0) base = atomicAdd(&ncand_sh, __popcll(m));
      base = __shfl(base, 0);
      if (match)
        cidx[base + __popcll(m & ((1ull << lane) - 1ull))] = (unsigned short)l;
    }
  }
  __syncthreads();
  int nc = ncand_sh < MAXC ? ncand_sh : MAXC;

  // ---- Stage 2a: window scoring (all 4 heads per k-row read) ----
  const float scale = 0.088388347648318447f;  // 1/sqrt(128)
  const float* kbase = key + (size_t)kh * S_LEN * D_DIM;
  if (tid < nw) {
    const float* kp = kbase + (size_t)widx[tid] * D_DIM;
    float a0 = 0.f, a1 = 0.f, a2 = 0.f, a3 = 0.f;
#pragma unroll 8
    for (int d = 0; d < D_DIM; d += 4) {
      float4 kv = *(const float4*)(kp + d);
      float4 q0 = *(const float4*)&q_sh[0][d];
      float4 q1 = *(const float4*)&q_sh[1][d];
      float4 q2 = *(const float4*)&q_sh[2][d];
      float4 q3 = *(const float4*)&q_sh[3][d];
      a0 += kv.x*q0.x + kv.y*q0.y + kv.z*q0.z + kv.w*q0.w;
      a1 += kv.x*q1.x + kv.y*q1.y + kv.z*q1.z + kv.w*q1.w;
      a2 += kv.x*q2.x + kv.y*q2.y + kv.z*q2.z + kv.w*q2.w;
      a3 += kv.x*q3.x + kv.y*q3.y + kv.z*q3.z + kv.w*q3.w;
    }
    wsc[0][tid] = a0*scale; wsc[1][tid] = a1*scale;
    wsc[2][tid] = a2*scale; wsc[3][tid] = a3*scale;
  }
  __syncthreads();

  // ---- Stage 2b: candidate scoring in 512-entry chunks -> wave registers ----
  float creg[NREG];
#pragma unroll
  for (int i = 0; i < NREG; i++) creg[i] = -1e30f;
#pragma unroll
  for (int cb = 0; cb < 4; cb++) {
    int base = cb * CHUNK;
    if (base < nc) {
#pragma unroll
      for (int t = 0; t < 2; t++) {
        int e = t * 256 + tid;
        int c = base + e;
        if (c < nc) {
          const float* kp = kbase + (size_t)cidx[c] * D_DIM;
          float a0 = 0.f, a1 = 0.f, a2 = 0.f, a3 = 0.f;
#pragma unroll 8
          for (int d = 0; d < D_DIM; d += 4) {
            float4 kv = *(const float4*)(kp + d);
            float4 q0 = *(const float4*)&q_sh[0][d];
            float4 q1 = *(const float4*)&q_sh[1][d];
            float4 q2 = *(const float4*)&q_sh[2][d];
            float4 q3 = *(const float4*)&q_sh[3][d];
            a0 += kv.x*q0.x + kv.y*q0.y + kv.z*q0.z + kv.w*q0.w;
            a1 += kv.x*q1.x + kv.y*q1.y + kv.z*q1.z + kv.w*q1.w;
            a2 += kv.x*q2.x + kv.y*q2.y + kv.z*q2.z + kv.w*q2.w;
            a3 += kv.x*q3.x + kv.y*q3.y + kv.z*q3.z + kv.w*q3.w;
          }
          cbuf[0][e] = a0*scale; cbuf[1][e] = a1*scale;
          cbuf[2][e] = a2*scale; cbuf[3][e] = a3*scale;
        }
      }
      __syncthreads();
#pragma unroll
      for (int j = 0; j < 8; j++)
        creg[cb * 8 + j] = cbuf[qh][j * 64 + lane];
      __syncthreads();
    }
  }
  const int imax = (nc + 63) >> 6;  // live creg slots

  // ---- Stage 3: per-wave exact top-k threshold (radix-64, no block barriers)
  bool selAll = (nc <= topk);
  unsigned int tkey = 0;
  bool useTie = false;
  int l_cut = S_LEN;
  if (!selAll) {
    unsigned int prefix = 0;
    int want = topk;
    for (int pass = 0; pass < 6; pass++) {
      int sh = 30 - pass * 6;  // 30,24,18,12,6,0
      hist[qh][lane] = 0;
      lds_fence();
#pragma unroll
      for (int i = 0; i < NREG; i++) {
        if (i >= imax) break;
        int c = lane + i * 64;
        if (c < nc) {
          unsigned int u = okey(creg[i]);
          bool match = (pass == 0) || ((u >> (sh + 6)) == prefix);
          if (match) atomicAdd(&hist[qh][(u >> sh) & 63u], 1u);
        }
      }
      lds_fence();
      unsigned int cnt = hist[qh][lane];
      unsigned int suf = cnt;  // suffix sum over digit bins
#pragma unroll
      for (int off = 1; off < 64; off <<= 1) {
        unsigned int t = __shfl_down(suf, off);
        if (lane + off < 64) suf += t;
      }
      unsigned long long mk = __ballot(suf >= (unsigned int)want);
      int dg = 63 - __clzll(mk);
      unsigned int suf_dg = __shfl(suf, dg);
      unsigned int cnt_dg = __shfl(cnt, dg);
      want -= (int)(suf_dg - cnt_dg);
      prefix = (prefix << 6) | (unsigned int)dg;
    }
    tkey = prefix;
    // exact tie handling (lowest l wins, matching lax.top_k)
    int cgt = 0, ceq = 0;
#pragma unroll
    for (int i = 0; i < NREG; i++) {
      if (i >= imax) break;
      int c = lane + i * 64;
      if (c < nc) {
        unsigned int u = okey(creg[i]);
        cgt += (u > tkey);
        ceq += (u == tkey);
      }
    }
#pragma unroll
    for (int off = 32; off > 0; off >>= 1) {
      cgt += __shfl_down(cgt, off);
      ceq += __shfl_down(ceq, off);
    }
    cgt = __shfl(cgt, 0); ceq = __shfl(ceq, 0);
    int rem = topk - cgt;
    if (ceq > rem) {
      useTie = true;
      int lo = 0, hi = S_LEN - 1;
      while (lo < hi) {
        int mid = (lo + hi) >> 1;
        int cn = 0;
#pragma unroll
        for (int i = 0; i < NREG; i++) {
          if (i >= imax) break;
          int c = lane + i * 64;
          if (c < nc) {
            unsigned int u = okey(creg[i]);
            cn += (u == tkey && (int)cidx[c] <= mid);
          }
        }
#pragma unroll
        for (int off = 32; off > 0; off >>= 1) cn += __shfl_down(cn, off);
        cn = __shfl(cn, 0);
        if (cn >= rem) hi = mid; else lo = mid + 1;
      }
      l_cut = lo;
    }
  }

  // ---- Stage 4: per-wave max, softmax + ballot-compacted (idx,p) list ----
  float mx = -1e30f;
#pragma unroll
  for (int i = 0; i < 3; i++) {
    int e = lane + i * 64;
    if (e < nw) mx = fmaxf(mx, wsc[qh][e]);
  }
#pragma unroll
  for (int i = 0; i < NREG; i++) {
    if (i >= imax) break;
    int c = lane + i * 64;
    if (c < nc) {
      float sc = creg[i];
      bool inc = selAll;
      if (!inc) {
        unsigned int u = okey(sc);
        inc = (u > tkey) || (u == tkey && (!useTie || (int)cidx[c] <= l_cut));
      }
      if (inc) mx = fmaxf(mx, sc);
    }
  }
#pragma unroll
  for (int off = 32; off > 0; off >>= 1) mx = fmaxf(mx, __shfl_down(mx, off));
  mx = __shfl(mx, 0);

  if (lane == 0) nsel_sh[qh] = 0;
  lds_fence();
  float sum = 0.0f;
#pragma unroll
  for (int i = 0; i < 3; i++) {
    int e = lane + i * 64;
    bool act = (e < nw);
    float p = 0.f; int idx = 0;
    if (act) { p = __expf(wsc[qh][e] - mx); sum += p; idx = widx[e]; }
    unsigned long long m = __ballot(act);
    if (m) {
      int base = 0;
      if (lane == 0) base = atomicAdd(&nsel_sh[qh], __popcll(m));
      base = __shfl(base, 0);
      if (act) {
        int pi = base + __popcll(m & ((1ull << lane) - 1ull));
        sel_idx[qh][pi] = (unsigned short)idx;
        sel_p[qh][pi] = p;
      }
    }
  }
#pragma unroll
  for (int i = 0; i < NREG; i++) {
    if (i >= imax) break;
    int c = lane + i * 64;
    bool act = false;
    float p = 0.f; int idx = 0;
    if (c < nc) {
      float sc = creg[i];
      bool inc = selAll;
      if (!inc) {
        unsigned int u = okey(sc);
        inc = (u > tkey) || (u == tkey && (!useTie || (int)cidx[c] <= l_cut));
      }
      if (inc) { act = true; p = __expf(sc - mx); sum += p; idx = cidx[c]; }
    }
    unsigned long long m = __ballot(act);
    if (m) {
      int base = 0;
      if (lane == 0) base = atomicAdd(&nsel_sh[qh], __popcll(m));
      base = __shfl(base, 0);
      if (act) {
        int pi = base + __popcll(m & ((1ull << lane) - 1ull));
        sel_idx[qh][pi] = (unsigned short)idx;
        sel_p[qh][pi] = p;
      }
    }
  }
#pragma unroll
  for (int off = 32; off > 0; off >>= 1) sum += __shfl_down(sum, off);
  sum = __shfl(sum, 0);
  float rinv = 1.0f / sum;

  lds_fence();
  int nsel = nsel_sh[qh];
  int nsel4 = (nsel + 3) & ~3;
  if (lane < nsel4 - nsel) {          // pad with p=0 entries
    sel_idx[qh][nsel + lane] = 0;
    sel_p[qh][nsel + lane] = 0.f;
  }
  lds_fence();

  // ---- Stage 5: PV accumulate, 4-way unrolled independent loads ----
  float accx = 0.f, accy = 0.f;
  const float* vbase = value + (size_t)kh * S_LEN * D_DIM + lane * 2;
  for (int e = 0; e < nsel4; e += 4) {
    int l0 = sel_idx[qh][e + 0], l1 = sel_idx[qh][e + 1];
    int l2 = sel_idx[qh][e + 2], l3 = sel_idx[qh][e + 3];
    float p0 = sel_p[qh][e + 0], p1 = sel_p[qh][e + 1];
    float p2 = sel_p[qh][e + 2], p3 = sel_p[qh][e + 3];
    float2 v0 = *(const float2*)(vbase + (size_t)l0 * D_DIM);
    float2 v1 = *(const float2*)(vbase + (size_t)l1 * D_DIM);
    float2 v2 = *(const float2*)(vbase + (size_t)l2 * D_DIM);
    float2 v3 = *(const float2*)(vbase + (size_t)l3 * D_DIM);
    accx += p0*v0.x + p1*v1.x + p2*v2.x + p3*v3.x;
    accy += p0*v0.y + p1*v1.y + p2*v2.y + p3*v3.y;
  }
  size_t o = (size_t)s * (H_N * D_DIM) + (size_t)(kh * QH_N + qh) * D_DIM + lane * 2;
  *(float2*)(out + o) = make_float2(accx * rinv, accy * rinv);
}

// ---------------------------------------------------------------------------
extern "C" void kernel_launch(void* const* d_in, const int* in_sizes, int n_in,
                              void* d_out, int out_size, void* d_ws, size_t ws_size,
                              hipStream_t stream) {
  const float* query = (const float*)d_in[0];
  const float* key   = (const float*)d_in[1];
  const float* value = (const float*)d_in[2];
  const float* thr   = (const float*)d_in[3];
  const int* p_topk  = (const int*)d_in[4];
  const int* p_wsz   = (const int*)d_in[5];
  float* out = (float*)d_out;
  unsigned long long* signs = (unsigned long long*)d_ws;  // (H+KH)*S*2 u64 = 640 KB

  int total_waves = (H_N + KH_N) * S_LEN;   // 40960
  pack_signs_kernel<<<total_waves / 4, 256, 0, stream>>>(query, key, signs);

  attn_kernel<<<KH_N * S_LEN, 256, 0, stream>>>(
      query, key, value, thr, p_topk, p_wsz, signs, out);
}

// Round 3
// 533.044 us; speedup vs baseline: 2.1714x; 1.0728x over previous
//
#include <hip/hip_runtime.h>

// Problem constants (fixed by setup_inputs)
#define S_LEN   2048
#define D_DIM   128
#define KH_N    4
#define QH_N    4
#define H_N     (KH_N * QH_N)
#define SINK_N  16
#define MAXW    160    // >= window(128) + sink(16)
#define MAXC    1904   // >= S - SINK - window
#define MAXT    2064   // unified list capacity (<=2048 used, padded to x16)
#define NREG    32     // ceil(2048/64) unified scores per lane
#define CHUNK   512    // rows scored per LDS chunk
#define MAXSEL  224    // >= window(144) + top_k(64)

typedef __attribute__((ext_vector_type(8))) short bf16x8;
typedef __attribute__((ext_vector_type(4))) float f32x4;

__device__ __forceinline__ void lds_fence() {
  asm volatile("s_waitcnt lgkmcnt(0)" ::: "memory");
}
__device__ __forceinline__ unsigned int okey(float f) {
  unsigned int b = __float_as_uint(f);
  return (b & 0x80000000u) ? ~b : (b | 0x80000000u);
}
__device__ __forceinline__ unsigned short f2bf(float f) {  // RNE truncate
  unsigned int u = __float_as_uint(f);
  u += 0x7FFFu + ((u >> 16) & 1u);
  return (unsigned short)(u >> 16);
}
__device__ __forceinline__ float bf2f(unsigned short h) {
  return __uint_as_float(((unsigned int)h) << 16);
}

// ---------------------------------------------------------------------------
// Kernel 1: pack sign bits into 2 x u64 per row; for KEY rows additionally
// emit hi/lo bf16 split of the row (256B hi + 256B lo, contiguous per row).
// Rows 0 .. H*S-1 = query rows; rows H*S .. +KH*S = key rows.
// ---------------------------------------------------------------------------
__global__ __launch_bounds__(256) void pack_signs_kernel(
    const float* __restrict__ q, const float* __restrict__ k,
    unsigned long long* __restrict__ signs, unsigned short* __restrict__ kbf) {
  int gid  = blockIdx.x * 256 + threadIdx.x;
  int wave = gid >> 6;
  int lane = gid & 63;
  const int QROWS = H_N * S_LEN;
  bool is_k = (wave >= QROWS);
  const float* src = !is_k ? (q + (size_t)wave * D_DIM)
                           : (k + (size_t)(wave - QROWS) * D_DIM);
  float v0 = src[lane], v1 = src[lane + 64];
  unsigned long long b0 = __ballot(v0 >= 0.0f);
  unsigned long long b1 = __ballot(v1 >= 0.0f);
  if (lane == 0) {
    signs[(size_t)wave * 2 + 0] = b0;
    signs[(size_t)wave * 2 + 1] = b1;
  }
  if (is_k) {
    int krow = wave - QROWS;
    unsigned short h0 = f2bf(v0), h1 = f2bf(v1);
    unsigned short l0 = f2bf(v0 - bf2f(h0)), l1 = f2bf(v1 - bf2f(h1));
    unsigned short* rb = kbf + (size_t)krow * 256;  // 128 hi then 128 lo
    rb[lane]       = h0;  rb[lane + 64]       = h1;
    rb[128 + lane] = l0;  rb[128 + 64 + lane] = l1;
  }
}

// ---------------------------------------------------------------------------
// Kernel 2: one block (4 waves) per (kh, s); wave == qh within the GQA group.
// Stage 2 scoring uses mfma_f32_16x16x32_bf16 with hi/lo split:
//   B cols 0-3 = q_hi*scale, cols 4-7 = q_lo*scale, 8-15 = 0
//   per K-slice: acc = mfma(k_hi, B, acc); acc = mfma(k_lo, B, acc)
//   score[m][h] = D[m][h] + D[m][h+4]   (shfl_xor by 4)
// ---------------------------------------------------------------------------
__global__ __launch_bounds__(256, 4) void attn_kernel(
    const float* __restrict__ query, const float* __restrict__ key,
    const float* __restrict__ value, const float* __restrict__ thr,
    const int* __restrict__ p_topk, const int* __restrict__ p_wsz,
    const unsigned long long* __restrict__ signs,
    const unsigned short* __restrict__ kbf,
    float* __restrict__ out) {
  const int row  = blockIdx.x;
  const int kh   = row >> 11;
  const int s    = (S_LEN - 1) - (row & (S_LEN - 1));  // big-s blocks first
  const int tid  = threadIdx.x;
  const int lane = tid & 63;
  const int qh   = tid >> 6;
  const int col  = lane & 15;
  const int quad = lane >> 4;

  __shared__ __align__(16) unsigned short q_bf[16][136];   // 4.25 KB (pad 272B)
  __shared__ unsigned long long qs_sh[QH_N][2];
  __shared__ unsigned short idx_sh[MAXT];                  // 4.1 KB
  __shared__ __align__(16) float cbuf[QH_N][CHUNK];        // 8 KB
  __shared__ unsigned int hist[QH_N][64];                  // 1 KB
  __shared__ unsigned short sel_idx[QH_N][MAXSEL];         // 1.75 KB
  __shared__ float sel_p[QH_N][MAXSEL];                    // 3.5 KB
  __shared__ int ncand_sh;
  __shared__ int nsel_sh[QH_N];

  const int   topk   = *p_topk;   // 64
  const int   wsz    = *p_wsz;    // 128
  const float thresh = thr[kh];   // 70.0
  const float scale  = 0.088388347648318447f;  // 1/sqrt(128)

  // ---- build q_bf (hi rows 0-3, lo rows 4-7, zeros 8-15), scale folded ----
  for (int i = tid; i < QH_N * D_DIM; i += 256) {
    int h = i >> 7, d = i & (D_DIM - 1);
    float f = query[((size_t)(kh * QH_N + h) * S_LEN + s) * D_DIM + d] * scale;
    unsigned short hi = f2bf(f);
    q_bf[h][d] = hi;
    q_bf[4 + h][d] = f2bf(f - bf2f(hi));
  }
  for (int i = tid; i < 8 * D_DIM; i += 256) q_bf[8 + (i >> 7)][i & (D_DIM - 1)] = 0;
  if (tid < QH_N * 2) {
    int h = tid >> 1, w = tid & 1;
    qs_sh[h][w] = signs[((size_t)(kh * QH_N + h) * S_LEN + s) * 2 + w];
  }
  if (tid == 0) ncand_sh = 0;

  // ---- window part of the unified list ----
  int wlo = s - (wsz - 1); if (wlo < 0) wlo = 0;
  int nsink = wlo < SINK_N ? wlo : SINK_N;
  int nw = nsink + (s - wlo + 1);
  if (nw > MAXW) nw = MAXW;
  for (int e = tid; e < nw; e += 256)
    idx_sh[e] = (unsigned short)(e < nsink ? e : wlo + (e - nsink));
  __syncthreads();

  // ---- Stage 1: LSH scan over [SINK, s-wsz] -> append candidates at nw ----
  unsigned long long qs0[QH_N], qs1[QH_N];
#pragma unroll
  for (int h = 0; h < QH_N; h++) { qs0[h] = qs_sh[h][0]; qs1[h] = qs_sh[h][1]; }
  const unsigned long long* ksg =
      signs + ((size_t)H_N * S_LEN + (size_t)kh * S_LEN) * 2;
  int lt_hi = s - wsz;  // inclusive
  for (int l0 = SINK_N; l0 <= lt_hi; l0 += 256) {
    int l = l0 + tid;
    bool match = false;
    if (l <= lt_hi) {
      ulonglong2 kk = *(const ulonglong2*)(ksg + 2 * l);
      int best = 0;
#pragma unroll
      for (int h = 0; h < QH_N; h++) {
        int m = 128 - __popcll(qs0[h] ^ kk.x) - __popcll(qs1[h] ^ kk.y);
        best = best > m ? best : m;
      }
      match = ((float)best > thresh);
    }
    unsigned long long m = __ballot(match);
    if (m) {
      int base = 0;
      if (lane == 0) base = atomicAdd(&ncand_sh, __popcll(m));
      base = __shfl(base, 0);
      if (match) {
        int pos = base + __popcll(m & ((1ull << lane) - 1ull));
        if (pos < MAXC) idx_sh[nw + pos] = (unsigned short)l;
      }
    }
  }
  __syncthreads();
  int nc = ncand_sh < MAXC ? ncand_sh : MAXC;
  int ntot = nw + nc;
  int ntot_pad = (ntot + 15) & ~15;
  for (int i = ntot + tid; i < ntot_pad; i += 256) idx_sh[i] = 0;  // pad rows
  __syncthreads();

  // ---- Stage 2: MFMA scoring of the unified list, chunked into cbuf ----
  bf16x8 bfrag[4];
#pragma unroll
  for (int ks = 0; ks < 4; ks++)
    bfrag[ks] = *(const bf16x8*)&q_bf[col][ks * 32 + quad * 8];

  const unsigned short* kbf_h = kbf + ((size_t)kh << 11) * 256;
  float creg[NREG];
#pragma unroll
  for (int i = 0; i < NREG; i++) creg[i] = -1e30f;

  for (int cb = 0; cb < 4; cb++) {
    int cbase = cb * CHUNK;
    int chunk_n = ntot_pad - cbase;
    if (chunk_n <= 0) break;
    if (chunk_n > CHUNK) chunk_n = CHUNK;
    int ntiles = chunk_n >> 4;
    for (int t = qh; t < ntiles; t += QH_N) {
      int tb = cbase + t * 16;
      int krow = idx_sh[tb + col];
      const unsigned char* ab =
          (const unsigned char*)(kbf_h + (size_t)krow * 256) + quad * 16;
      bf16x8 ah0 = *(const bf16x8*)(ab + 0);
      bf16x8 ah1 = *(const bf16x8*)(ab + 64);
      bf16x8 ah2 = *(const bf16x8*)(ab + 128);
      bf16x8 ah3 = *(const bf16x8*)(ab + 192);
      bf16x8 al0 = *(const bf16x8*)(ab + 256);
      bf16x8 al1 = *(const bf16x8*)(ab + 320);
      bf16x8 al2 = *(const bf16x8*)(ab + 384);
      bf16x8 al3 = *(const bf16x8*)(ab + 448);
      f32x4 acc = {0.f, 0.f, 0.f, 0.f};
      acc = __builtin_amdgcn_mfma_f32_16x16x32_bf16(ah0, bfrag[0], acc, 0, 0, 0);
      acc = __builtin_amdgcn_mfma_f32_16x16x32_bf16(al0, bfrag[0], acc, 0, 0, 0);
      acc = __builtin_amdgcn_mfma_f32_16x16x32_bf16(ah1, bfrag[1], acc, 0, 0, 0);
      acc = __builtin_amdgcn_mfma_f32_16x16x32_bf16(al1, bfrag[1], acc, 0, 0, 0);
      acc = __builtin_amdgcn_mfma_f32_16x16x32_bf16(ah2, bfrag[2], acc, 0, 0, 0);
      acc = __builtin_amdgcn_mfma_f32_16x16x32_bf16(al2, bfrag[2], acc, 0, 0, 0);
      acc = __builtin_amdgcn_mfma_f32_16x16x32_bf16(ah3, bfrag[3], acc, 0, 0, 0);
      acc = __builtin_amdgcn_mfma_f32_16x16x32_bf16(al3, bfrag[3], acc, 0, 0, 0);
      // score[m][h] = D[m][h] + D[m][h+4]; rows m = quad*4 + r
      f32x4 t4;
#pragma unroll
      for (int r = 0; r < 4; r++) t4[r] = acc[r] + __shfl_xor(acc[r], 4);
      if (col < 4)
        *(f32x4*)&cbuf[col][(tb - cbase) + quad * 4] = t4;
    }
    __syncthreads();
#pragma unroll
    for (int j = 0; j < 8; j++) {
      int v = j * 64 + lane;
      if (v < chunk_n) creg[cb * 8 + j] = cbuf[qh][v];
    }
    __syncthreads();
  }
  const int imax = (ntot + 63) >> 6;

  // ---- Stage 3: per-wave exact top-k threshold over candidates ----
  bool selAll = (nc <= topk);
  unsigned int tkey = 0;
  bool useTie = false;
  int l_cut = S_LEN;
  if (!selAll) {
    unsigned int prefix = 0;
    int want = topk;
    for (int pass = 0; pass < 6; pass++) {
      int sh = 30 - pass * 6;
      hist[qh][lane] = 0;
      lds_fence();
#pragma unroll
      for (int i = 0; i < NREG; i++) {
        if (i >= imax) break;
        int e = lane + i * 64;
        if (e >= nw && e < ntot) {
          unsigned int u = okey(creg[i]);
          bool match = (pass == 0) || ((u >> (sh + 6)) == prefix);
          if (match) atomicAdd(&hist[qh][(u >> sh) & 63u], 1u);
        }
      }
      lds_fence();
      unsigned int cnt = hist[qh][lane];
      unsigned int suf = cnt;
#pragma unroll
      for (int off = 1; off < 64; off <<= 1) {
        unsigned int t = __shfl_down(suf, off);
        if (lane + off < 64) suf += t;
      }
      unsigned long long mk = __ballot(suf >= (unsigned int)want);
      int dg = 63 - __clzll(mk);
      unsigned int suf_dg = __shfl(suf, dg);
      unsigned int cnt_dg = __shfl(cnt, dg);
      want -= (int)(suf_dg - cnt_dg);
      prefix = (prefix << 6) | (unsigned int)dg;
    }
    tkey = prefix;
    int cgt = 0, ceq = 0;
#pragma unroll
    for (int i = 0; i < NREG; i++) {
      if (i >= imax) break;
      int e = lane + i * 64;
      if (e >= nw && e < ntot) {
        unsigned int u = okey(creg[i]);
        cgt += (u > tkey);
        ceq += (u == tkey);
      }
    }
#pragma unroll
    for (int off = 32; off > 0; off >>= 1) {
      cgt += __shfl_down(cgt, off);
      ceq += __shfl_down(ceq, off);
    }
    cgt = __shfl(cgt, 0); ceq = __shfl(ceq, 0);
    int rem = topk - cgt;
    if (ceq > rem) {  // exact ties: lowest l wins (matches lax.top_k)
      useTie = true;
      int lo = 0, hi = S_LEN - 1;
      while (lo < hi) {
        int mid = (lo + hi) >> 1;
        int cn = 0;
#pragma unroll
        for (int i = 0; i < NREG; i++) {
          if (i >= imax) break;
          int e = lane + i * 64;
          if (e >= nw && e < ntot) {
            unsigned int u = okey(creg[i]);
            cn += (u == tkey && (int)idx_sh[e] <= mid);
          }
        }
#pragma unroll
        for (int off = 32; off > 0; off >>= 1) cn += __shfl_down(cn, off);
        cn = __shfl(cn, 0);
        if (cn >= rem) hi = mid; else lo = mid + 1;
      }
      l_cut = lo;
    }
  }

  // ---- Stage 4: per-wave max, softmax + ballot-compacted (idx,p) list ----
  float mx = -1e30f;
#pragma unroll
  for (int i = 0; i < NREG; i++) {
    if (i >= imax) break;
    int e = lane + i * 64;
    if (e < ntot) {
      float sc = creg[i];
      bool inc = (e < nw) || selAll;
      if (!inc) {
        unsigned int u = okey(sc);
        inc = (u > tkey) || (u == tkey && (!useTie || (int)idx_sh[e] <= l_cut));
      }
      if (inc) mx = fmaxf(mx, sc);
    }
  }
#pragma unroll
  for (int off = 32; off > 0; off >>= 1) mx = fmaxf(mx, __shfl_down(mx, off));
  mx = __shfl(mx, 0);

  if (lane == 0) nsel_sh[qh] = 0;
  lds_fence();
  float sum = 0.0f;
#pragma unroll
  for (int i = 0; i < NREG; i++) {
    if (i >= imax) break;
    int e = lane + i * 64;
    bool act = false;
    float p = 0.f;
    if (e < ntot) {
      float sc = creg[i];
      bool inc = (e < nw) || selAll;
      if (!inc) {
        unsigned int u = okey(sc);
        inc = (u > tkey) || (u == tkey && (!useTie || (int)idx_sh[e] <= l_cut));
      }
      if (inc) { act = true; p = __expf(sc - mx); sum += p; }
    }
    unsigned long long m = __ballot(act);
    if (m) {
      int base = 0;
      if (lane == 0) base = atomicAdd(&nsel_sh[qh], __popcll(m));
      base = __shfl(base, 0);
      if (act) {
        int pi = base + __popcll(m & ((1ull << lane) - 1ull));
        sel_idx[qh][pi] = idx_sh[e];
        sel_p[qh][pi] = p;
      }
    }
  }
#pragma unroll
  for (int off = 32; off > 0; off >>= 1) sum += __shfl_down(sum, off);
  sum = __shfl(sum, 0);
  float rinv = 1.0f / sum;

  lds_fence();
  int nsel = nsel_sh[qh];
  int nsel4 = (nsel + 3) & ~3;
  if (lane < nsel4 - nsel) {  // pad with p=0
    sel_idx[qh][nsel + lane] = 0;
    sel_p[qh][nsel + lane] = 0.f;
  }
  lds_fence();

  // ---- Stage 5: PV accumulate, 4-way unrolled ----
  float accx = 0.f, accy = 0.f;
  const float* vbase = value + (size_t)kh * S_LEN * D_DIM + lane * 2;
  for (int e = 0; e < nsel4; e += 4) {
    int l0 = sel_idx[qh][e + 0], l1 = sel_idx[qh][e + 1];
    int l2 = sel_idx[qh][e + 2], l3 = sel_idx[qh][e + 3];
    float p0 = sel_p[qh][e + 0], p1 = sel_p[qh][e + 1];
    float p2 = sel_p[qh][e + 2], p3 = sel_p[qh][e + 3];
    float2 v0 = *(const float2*)(vbase + (size_t)l0 * D_DIM);
    float2 v1 = *(const float2*)(vbase + (size_t)l1 * D_DIM);
    float2 v2 = *(const float2*)(vbase + (size_t)l2 * D_DIM);
    float2 v3 = *(const float2*)(vbase + (size_t)l3 * D_DIM);
    accx += p0*v0.x + p1*v1.x + p2*v2.x + p3*v3.x;
    accy += p0*v0.y + p1*v1.y + p2*v2.y + p3*v3.y;
  }
  size_t o = (size_t)s * (H_N * D_DIM) + (size_t)(kh * QH_N + qh) * D_DIM + lane * 2;
  *(float2*)(out + o) = make_float2(accx * rinv, accy * rinv);
}

// ---------------------------------------------------------------------------
extern "C" void kernel_launch(void* const* d_in, const int* in_sizes, int n_in,
                              void* d_out, int out_size, void* d_ws, size_t ws_size,
                              hipStream_t stream) {
  const float* query = (const float*)d_in[0];
  const float* key   = (const float*)d_in[1];
  const float* value = (const float*)d_in[2];
  const float* thr   = (const float*)d_in[3];
  const int* p_topk  = (const int*)d_in[4];
  const int* p_wsz   = (const int*)d_in[5];
  float* out = (float*)d_out;

  // ws layout: signs (40960 rows * 16B = 640 KB) | kbf (8192 rows * 512B = 4 MB)
  unsigned long long* signs = (unsigned long long*)d_ws;
  unsigned short* kbf = (unsigned short*)((char*)d_ws + (size_t)(H_N + KH_N) * S_LEN * 16);

  int total_waves = (H_N + KH_N) * S_LEN;   // 40960
  pack_signs_kernel<<<total_waves / 4, 256, 0, stream>>>(query, key, signs, kbf);

  attn_kernel<<<KH_N * S_LEN, 256, 0, stream>>>(
      query, key, value, thr, p_topk, p_wsz, signs, kbf, out);
}

// Round 4
// 415.124 us; speedup vs baseline: 2.7882x; 1.2841x over previous
//
#include <hip/hip_runtime.h>

// Problem constants (fixed by setup_inputs)
#define S_LEN   2048
#define D_DIM   128
#define KH_N    4
#define QH_N    4
#define H_N     (KH_N * QH_N)
#define SINK_N  16
#define MAXW    160    // >= window(128) + sink(16)
#define MAXC    1904   // >= S - SINK - window
#define MAXT    2064   // unified list capacity (padded to x16)
#define NREG    32     // ceil(2048/64) unified scores per lane
#define CHUNK   512    // rows scored per LDS chunk
#define MAXSEL  224    // >= window(144) + top_k(64), multiple of 8

typedef __attribute__((ext_vector_type(8))) short bf16x8;
typedef __attribute__((ext_vector_type(4))) float f32x4;

__device__ __forceinline__ void lds_fence() {
  asm volatile("s_waitcnt lgkmcnt(0)" ::: "memory");
}
__device__ __forceinline__ unsigned int okey(float f) {
  unsigned int b = __float_as_uint(f);
  return (b & 0x80000000u) ? ~b : (b | 0x80000000u);
}
__device__ __forceinline__ unsigned short f2bf(float f) {  // RNE
  unsigned int u = __float_as_uint(f);
  u += 0x7FFFu + ((u >> 16) & 1u);
  return (unsigned short)(u >> 16);
}
__device__ __forceinline__ float bf2f(unsigned short h) {
  return __uint_as_float(((unsigned int)h) << 16);
}

// ---------------------------------------------------------------------------
// Kernel 1: per wave, 8 rows. Row space: [0,32768) q rows (signs),
// [32768,40960) k rows (signs + bf16 hi/lo planes), [40960,49152) v rows
// (bf16 plane). Boundaries are multiples of 8 -> wave-uniform row type.
// ---------------------------------------------------------------------------
__global__ __launch_bounds__(256) void pack_kernel(
    const float* __restrict__ q, const float* __restrict__ k,
    const float* __restrict__ v,
    unsigned long long* __restrict__ signs,
    unsigned short* __restrict__ kbf, unsigned int* __restrict__ vbf) {
  int wid  = (blockIdx.x * 256 + threadIdx.x) >> 6;
  int lane = threadIdx.x & 63;
  int rbase = wid * 8;
  const int QROWS = H_N * S_LEN;            // 32768
  const int KROWS = KH_N * S_LEN;           // 8192
#pragma unroll
  for (int r8 = 0; r8 < 8; r8++) {
    int row = rbase + r8;
    if (row < QROWS) {
      const float* src = q + (size_t)row * D_DIM;
      float v0 = src[lane], v1 = src[lane + 64];
      unsigned long long b0 = __ballot(v0 >= 0.0f);
      unsigned long long b1 = __ballot(v1 >= 0.0f);
      if (lane == 0) { signs[(size_t)row*2] = b0; signs[(size_t)row*2+1] = b1; }
    } else if (row < QROWS + KROWS) {
      int kr = row - QROWS;
      const float* src = k + (size_t)kr * D_DIM;
      float v0 = src[lane], v1 = src[lane + 64];
      unsigned long long b0 = __ballot(v0 >= 0.0f);
      unsigned long long b1 = __ballot(v1 >= 0.0f);
      if (lane == 0) { signs[(size_t)row*2] = b0; signs[(size_t)row*2+1] = b1; }
      unsigned short h0 = f2bf(v0), h1 = f2bf(v1);
      unsigned short l0 = f2bf(v0 - bf2f(h0)), l1 = f2bf(v1 - bf2f(h1));
      unsigned short* rb = kbf + (size_t)kr * 256;  // 128 hi then 128 lo
      rb[lane]       = h0;  rb[lane + 64]       = h1;
      rb[128 + lane] = l0;  rb[192 + lane]      = l1;
    } else {
      int vr = row - QROWS - KROWS;
      float2 f2 = *(const float2*)(v + (size_t)vr * D_DIM + lane * 2);
      unsigned int pk = (unsigned int)f2bf(f2.x) | ((unsigned int)f2bf(f2.y) << 16);
      vbf[(size_t)vr * 64 + lane] = pk;
    }
  }
}

// ---------------------------------------------------------------------------
// Kernel 2: one block (4 waves) per (kh, s); wave == qh within the GQA group.
// ---------------------------------------------------------------------------
__global__ __launch_bounds__(256, 4) void attn_kernel(
    const float* __restrict__ query, const float* __restrict__ thr,
    const int* __restrict__ p_topk, const int* __restrict__ p_wsz,
    const unsigned long long* __restrict__ signs,
    const unsigned short* __restrict__ kbf,
    const unsigned int* __restrict__ vbf,
    float* __restrict__ out) {
  const int row  = blockIdx.x;
  const int kh   = row >> 11;
  const int s    = (S_LEN - 1) - (row & (S_LEN - 1));  // big-s blocks first
  const int tid  = threadIdx.x;
  const int lane = tid & 63;
  const int qh   = tid >> 6;
  const int col  = lane & 15;
  const int quad = lane >> 4;

  __shared__ __align__(16) unsigned short q_bf[8][136];    // 2.1 KB
  __shared__ unsigned long long qs_sh[QH_N][2];
  __shared__ unsigned short idx_sh[MAXT];                  // 4.1 KB
  __shared__ __align__(16) float cbuf[QH_N][CHUNK];        // 8 KB
  __shared__ unsigned int hist[QH_N][256];                 // 4 KB
  __shared__ unsigned short sel_idx[QH_N][MAXSEL];         // 1.75 KB
  __shared__ float sel_p[QH_N][MAXSEL];                    // 3.5 KB
  __shared__ int ncand_sh;
  __shared__ int nsel_sh[QH_N];

  const int   topk   = *p_topk;   // 64
  const int   wsz    = *p_wsz;    // 128
  const float thresh = thr[kh];   // 70.0
  const float scale  = 0.088388347648318447f;  // 1/sqrt(128)

  // ---- build q_bf (hi rows 0-3, lo rows 4-7), scale folded ----
  for (int i = tid; i < QH_N * D_DIM; i += 256) {
    int h = i >> 7, d = i & (D_DIM - 1);
    float f = query[((size_t)(kh * QH_N + h) * S_LEN + s) * D_DIM + d] * scale;
    unsigned short hi = f2bf(f);
    q_bf[h][d] = hi;
    q_bf[4 + h][d] = f2bf(f - bf2f(hi));
  }
  if (tid < QH_N * 2) {
    int h = tid >> 1, w = tid & 1;
    qs_sh[h][w] = signs[((size_t)(kh * QH_N + h) * S_LEN + s) * 2 + w];
  }
  if (tid == 0) ncand_sh = 0;

  // ---- window part of the unified list ----
  int wlo = s - (wsz - 1); if (wlo < 0) wlo = 0;
  int nsink = wlo < SINK_N ? wlo : SINK_N;
  int nw = nsink + (s - wlo + 1);
  if (nw > MAXW) nw = MAXW;
  for (int e = tid; e < nw; e += 256)
    idx_sh[e] = (unsigned short)(e < nsink ? e : wlo + (e - nsink));
  __syncthreads();

  // ---- Stage 1: LSH scan over [SINK, s-wsz] -> append candidates at nw ----
  unsigned long long qs0[QH_N], qs1[QH_N];
#pragma unroll
  for (int h = 0; h < QH_N; h++) { qs0[h] = qs_sh[h][0]; qs1[h] = qs_sh[h][1]; }
  const unsigned long long* ksg =
      signs + ((size_t)H_N * S_LEN + (size_t)kh * S_LEN) * 2;
  int lt_hi = s - wsz;  // inclusive
  for (int l0 = SINK_N; l0 <= lt_hi; l0 += 256) {
    int l = l0 + tid;
    bool match = false;
    if (l <= lt_hi) {
      ulonglong2 kk = *(const ulonglong2*)(ksg + 2 * l);
      int best = 0;
#pragma unroll
      for (int h = 0; h < QH_N; h++) {
        int m = 128 - __popcll(qs0[h] ^ kk.x) - __popcll(qs1[h] ^ kk.y);
        best = best > m ? best : m;
      }
      match = ((float)best > thresh);
    }
    unsigned long long m = __ballot(match);
    if (m) {
      int base = 0;
      if (lane == 0) base = atomicAdd(&ncand_sh, __popcll(m));
      base = __shfl(base, 0);
      if (match) {
        int pos = base + __popcll(m & ((1ull << lane) - 1ull));
        if (pos < MAXC) idx_sh[nw + pos] = (unsigned short)l;
      }
    }
  }
  __syncthreads();
  int nc = ncand_sh < MAXC ? ncand_sh : MAXC;
  int ntot = nw + nc;
  int ntot_pad = (ntot + 15) & ~15;
  for (int i = ntot + tid; i < ntot_pad; i += 256) idx_sh[i] = 0;
  __syncthreads();

  // ---- Stage 2: MFMA scoring (hi/lo bf16 split), chunked into cbuf ----
  bf16x8 bfrag[4];
  bf16x8 bzero = {0, 0, 0, 0, 0, 0, 0, 0};
#pragma unroll
  for (int ks = 0; ks < 4; ks++)
    bfrag[ks] = (col < 8) ? *(const bf16x8*)&q_bf[col][ks * 32 + quad * 8] : bzero;

  const unsigned short* kbf_h = kbf + ((size_t)kh << 11) * 256;
  float creg[NREG];
#pragma unroll
  for (int i = 0; i < NREG; i++) creg[i] = -1e30f;

  for (int cb = 0; cb < 4; cb++) {
    int cbase = cb * CHUNK;
    int chunk_n = ntot_pad - cbase;
    if (chunk_n <= 0) break;
    if (chunk_n > CHUNK) chunk_n = CHUNK;
    int ntiles = chunk_n >> 4;
    for (int t = qh; t < ntiles; t += QH_N) {
      int tb = cbase + t * 16;
      int krow = idx_sh[tb + col];
      const unsigned char* ab =
          (const unsigned char*)(kbf_h + (size_t)krow * 256) + quad * 16;
      bf16x8 ah0 = *(const bf16x8*)(ab + 0);
      bf16x8 ah1 = *(const bf16x8*)(ab + 64);
      bf16x8 ah2 = *(const bf16x8*)(ab + 128);
      bf16x8 ah3 = *(const bf16x8*)(ab + 192);
      bf16x8 al0 = *(const bf16x8*)(ab + 256);
      bf16x8 al1 = *(const bf16x8*)(ab + 320);
      bf16x8 al2 = *(const bf16x8*)(ab + 384);
      bf16x8 al3 = *(const bf16x8*)(ab + 448);
      f32x4 acc = {0.f, 0.f, 0.f, 0.f};
      acc = __builtin_amdgcn_mfma_f32_16x16x32_bf16(ah0, bfrag[0], acc, 0, 0, 0);
      acc = __builtin_amdgcn_mfma_f32_16x16x32_bf16(al0, bfrag[0], acc, 0, 0, 0);
      acc = __builtin_amdgcn_mfma_f32_16x16x32_bf16(ah1, bfrag[1], acc, 0, 0, 0);
      acc = __builtin_amdgcn_mfma_f32_16x16x32_bf16(al1, bfrag[1], acc, 0, 0, 0);
      acc = __builtin_amdgcn_mfma_f32_16x16x32_bf16(ah2, bfrag[2], acc, 0, 0, 0);
      acc = __builtin_amdgcn_mfma_f32_16x16x32_bf16(al2, bfrag[2], acc, 0, 0, 0);
      acc = __builtin_amdgcn_mfma_f32_16x16x32_bf16(ah3, bfrag[3], acc, 0, 0, 0);
      acc = __builtin_amdgcn_mfma_f32_16x16x32_bf16(al3, bfrag[3], acc, 0, 0, 0);
      f32x4 t4;
#pragma unroll
      for (int r = 0; r < 4; r++) t4[r] = acc[r] + __shfl_xor(acc[r], 4);
      if (col < 4)
        *(f32x4*)&cbuf[col][(tb - cbase) + quad * 4] = t4;
    }
    __syncthreads();
#pragma unroll
    for (int j = 0; j < 8; j++) {
      int v = j * 64 + lane;
      if (v < chunk_n) creg[cb * 8 + j] = cbuf[qh][v];
    }
    __syncthreads();
  }
  const int imax = (ntot + 63) >> 6;

  // ---- cheap exact max: max over ALL scores == max over included set ----
  float mx = -1e30f;
#pragma unroll
  for (int i = 0; i < NREG; i++) {
    if (i >= imax) break;
    int e = lane + i * 64;
    if (e < ntot) mx = fmaxf(mx, creg[i]);
  }
#pragma unroll
  for (int off = 32; off > 0; off >>= 1) mx = fmaxf(mx, __shfl_down(mx, off));
  mx = __shfl(mx, 0);

  // ---- Stage 3: per-wave exact top-k threshold (radix-256, 4 passes) ----
  bool selAll = (nc <= topk);
  unsigned int tkey = 0;
  bool useTie = false;
  int l_cut = S_LEN;
  if (!selAll) {
    unsigned int prefix = 0;
    int want = topk;
    for (int pass = 0; pass < 4; pass++) {
      int sh = 24 - pass * 8;
#pragma unroll
      for (int j = 0; j < 4; j++) hist[qh][lane * 4 + j] = 0;
      lds_fence();
#pragma unroll
      for (int i = 0; i < NREG; i++) {
        if (i >= imax) break;
        int e = lane + i * 64;
        if (e >= nw && e < ntot) {
          unsigned int u = okey(creg[i]);
          bool match = (pass == 0) || ((u >> (sh + 8)) == prefix);
          if (match) atomicAdd(&hist[qh][(u >> sh) & 255u], 1u);
        }
      }
      lds_fence();
      unsigned int c0 = hist[qh][lane * 4 + 0];
      unsigned int c1 = hist[qh][lane * 4 + 1];
      unsigned int c2 = hist[qh][lane * 4 + 2];
      unsigned int c3 = hist[qh][lane * 4 + 3];
      unsigned int S3 = c3, S2 = c2 + S3, S1 = c1 + S2, S0 = c0 + S1;
      unsigned int tot = S0;
      unsigned int suf = tot;
#pragma unroll
      for (int off = 1; off < 64; off <<= 1) {
        unsigned int t = __shfl_down(suf, off);
        if (lane + off < 64) suf += t;
      }
      unsigned long long mk = __ballot(suf >= (unsigned int)want);
      int L = 63 - __clzll(mk);
      // each lane computes digit/new-want as if it were chosen, then shfl
      unsigned int se = suf - tot;
      unsigned int s3 = S3 + se, s2 = S2 + se, s1 = S1 + se, s0 = S0 + se;
      int j; unsigned int above;
      unsigned int w = (unsigned int)want;
      if (s3 >= w)      { j = 3; above = s3 - c3; }
      else if (s2 >= w) { j = 2; above = s2 - c2; }
      else if (s1 >= w) { j = 1; above = s1 - c1; }
      else              { j = 0; above = s0 - c0; }
      int d_me = (lane << 2) | j;
      int wp_me = want - (int)above;
      int digit = __shfl(d_me, L);
      want = __shfl(wp_me, L);
      prefix = (prefix << 8) | (unsigned int)digit;
    }
    tkey = prefix;
    // exact tie handling (lowest l wins, matching lax.top_k)
    int cgt = 0, ceq = 0;
#pragma unroll
    for (int i = 0; i < NREG; i++) {
      if (i >= imax) break;
      int e = lane + i * 64;
      if (e >= nw && e < ntot) {
        unsigned int u = okey(creg[i]);
        cgt += (u > tkey);
        ceq += (u == tkey);
      }
    }
#pragma unroll
    for (int off = 32; off > 0; off >>= 1) {
      cgt += __shfl_down(cgt, off);
      ceq += __shfl_down(ceq, off);
    }
    cgt = __shfl(cgt, 0); ceq = __shfl(ceq, 0);
    int rem = topk - cgt;
    if (ceq > rem) {
      useTie = true;
      int lo = 0, hi = S_LEN - 1;
      while (lo < hi) {
        int mid = (lo + hi) >> 1;
        int cn = 0;
#pragma unroll
        for (int i = 0; i < NREG; i++) {
          if (i >= imax) break;
          int e = lane + i * 64;
          if (e >= nw && e < ntot) {
            unsigned int u = okey(creg[i]);
            cn += (u == tkey && (int)idx_sh[e] <= mid);
          }
        }
#pragma unroll
        for (int off = 32; off > 0; off >>= 1) cn += __shfl_down(cn, off);
        cn = __shfl(cn, 0);
        if (cn >= rem) hi = mid; else lo = mid + 1;
      }
      l_cut = lo;
    }
  }

  // ---- Stage 4: fused select + exp + ballot-compact (single pass) ----
  if (lane == 0) nsel_sh[qh] = 0;
  lds_fence();
  float sum = 0.0f;
#pragma unroll
  for (int i = 0; i < NREG; i++) {
    if (i >= imax) break;
    int e = lane + i * 64;
    bool act = false;
    float p = 0.f;
    if (e < ntot) {
      float sc = creg[i];
      bool inc = (e < nw) || selAll;
      if (!inc) {
        unsigned int u = okey(sc);
        inc = (u > tkey) || (u == tkey && (!useTie || (int)idx_sh[e] <= l_cut));
      }
      if (inc) { act = true; p = __expf(sc - mx); sum += p; }
    }
    unsigned long long m = __ballot(act);
    if (m) {
      int base = 0;
      if (lane == 0) base = atomicAdd(&nsel_sh[qh], __popcll(m));
      base = __shfl(base, 0);
      if (act) {
        int pi = base + __popcll(m & ((1ull << lane) - 1ull));
        sel_idx[qh][pi] = idx_sh[e];
        sel_p[qh][pi] = p;
      }
    }
  }
#pragma unroll
  for (int off = 32; off > 0; off >>= 1) sum += __shfl_down(sum, off);
  sum = __shfl(sum, 0);
  float rinv = 1.0f / sum;

  lds_fence();
  int nsel = nsel_sh[qh];
  int nsel8 = (nsel + 7) & ~7;
  if (lane < nsel8 - nsel) {  // pad with p=0
    sel_idx[qh][nsel + lane] = 0;
    sel_p[qh][nsel + lane] = 0.f;
  }
  lds_fence();

  // ---- Stage 5: PV accumulate over bf16 V, 8-way unrolled ----
  float accx = 0.f, accy = 0.f;
  const unsigned int* vb = vbf + ((size_t)kh << 11) * 64 + lane;
  for (int e = 0; e < nsel8; e += 8) {
    unsigned int dv[8]; float pv[8];
#pragma unroll
    for (int j = 0; j < 8; j++) {
      int l = sel_idx[qh][e + j];
      pv[j] = sel_p[qh][e + j];
      dv[j] = vb[(size_t)l * 64];
    }
#pragma unroll
    for (int j = 0; j < 8; j++) {
      accx += pv[j] * __uint_as_float(dv[j] << 16);
      accy += pv[j] * __uint_as_float(dv[j] & 0xFFFF0000u);
    }
  }
  size_t o = (size_t)s * (H_N * D_DIM) + (size_t)(kh * QH_N + qh) * D_DIM + lane * 2;
  *(float2*)(out + o) = make_float2(accx * rinv, accy * rinv);
}

// ---------------------------------------------------------------------------
extern "C" void kernel_launch(void* const* d_in, const int* in_sizes, int n_in,
                              void* d_out, int out_size, void* d_ws, size_t ws_size,
                              hipStream_t stream) {
  const float* query = (const float*)d_in[0];
  const float* key   = (const float*)d_in[1];
  const float* value = (const float*)d_in[2];
  const float* thr   = (const float*)d_in[3];
  const int* p_topk  = (const int*)d_in[4];
  const int* p_wsz   = (const int*)d_in[5];
  float* out = (float*)d_out;

  // ws layout: signs 40960*16B = 640 KB | kbf 8192*512B = 4 MB | vbf 8192*256B = 2 MB
  char* ws = (char*)d_ws;
  unsigned long long* signs = (unsigned long long*)ws;
  unsigned short* kbf = (unsigned short*)(ws + (size_t)(H_N + KH_N) * S_LEN * 16);
  unsigned int* vbf = (unsigned int*)(ws + (size_t)(H_N + KH_N) * S_LEN * 16
                                         + (size_t)KH_N * S_LEN * 512);

  // 49152 rows total, 8 rows per wave, 4 waves per block -> 1536 blocks
  pack_kernel<<<1536, 256, 0, stream>>>(query, key, value, signs, kbf, vbf);

  attn_kernel<<<KH_N * S_LEN, 256, 0, stream>>>(
      query, thr, p_topk, p_wsz, signs, kbf, vbf, out);
}